// Round 1
// baseline (57.693 us; speedup 1.0000x reference)
//
#include <hip/hip_runtime.h>
#include <hip/hip_bf16.h>

// PTMLoss: loss0 (per-row distance-to-origin term) + mean over upper-tri
// pairwise-distance terms. Strategy: bf16 MFMA Gram matrix (value-safe since
// only the mean is output; sq kept fp32), deterministic hierarchical reduce.

#define NROWS 8192
#define DDIM  128
#define TILE  128
#define TTILES (NROWS / TILE)   // 64
#define FEPS  1e-6f

typedef float f32x4 __attribute__((ext_vector_type(4)));
typedef short s16x8 __attribute__((ext_vector_type(8)));

__device__ __forceinline__ float pe_clip_from_rinv(float r) {
    // r = 1/d ; pe = 1/d^3 - 1/d^2 = r^3 - r^2 ; clip to [-1.5, 1000]
    float r2 = r * r;
    float v = r2 * r - r2;
    return fminf(fmaxf(v, -1.5f), 1000.0f);
}

// One wave per row: bf16 convert + fp32 row sum-of-squares + loss0 partial.
__global__ __launch_bounds__(256) void convert_kernel(
        const float* __restrict__ x, unsigned int* __restrict__ xb_u32,
        float* __restrict__ sq, float* __restrict__ p0) {
    int tid = threadIdx.x;
    int wave = tid >> 6, lane = tid & 63;
    int row = blockIdx.x * 4 + wave;

    float2 v = *(const float2*)(x + (size_t)row * DDIM + lane * 2);
    float s = v.x * v.x + v.y * v.y;
    float ex = v.x + FEPS, ey = v.y + FEPS;
    float e = ex * ex + ey * ey;

    // pack 2 bf16 into one u32, coalesced 4B/lane
    __hip_bfloat16 b0 = __float2bfloat16(v.x);
    __hip_bfloat16 b1 = __float2bfloat16(v.y);
    unsigned short u0 = *reinterpret_cast<unsigned short*>(&b0);
    unsigned short u1 = *reinterpret_cast<unsigned short*>(&b1);
    xb_u32[(size_t)row * (DDIM / 2) + lane] = (unsigned)u0 | ((unsigned)u1 << 16);

    #pragma unroll
    for (int off = 32; off; off >>= 1) {
        s += __shfl_down(s, off);
        e += __shfl_down(e, off);
    }

    __shared__ float red[4];
    if (lane == 0) {
        sq[row] = s;
        red[wave] = pe_clip_from_rinv(rsqrtf(e));  // d0 = sqrt(e), r = 1/d0
    }
    __syncthreads();
    if (tid == 0) p0[blockIdx.x] = red[0] + red[1] + red[2] + red[3];
}

// One 128x128 tile of S = X X^T per block; triangular grid (J >= I active).
__global__ __launch_bounds__(256) void pair_kernel(
        const __hip_bfloat16* __restrict__ xb,
        const float* __restrict__ sq, float* __restrict__ pp) {
    int I = blockIdx.y, J = blockIdx.x;
    int bid = I * TTILES + J;
    int tid = threadIdx.x;
    if (J < I) { if (tid == 0) pp[bid] = 0.0f; return; }

    __shared__ char smem[65536];
    char* ldsA = smem;
    char* ldsB = smem + 32768;

    // ---- stage both 128x128 bf16 tiles into LDS with XOR swizzle ----
    {
        int chunk = tid & 15;          // 16 chunks of 16B per 256B row
        int r0 = tid >> 4;             // 16 rows per pass
        const char* gA = (const char*)(xb + (size_t)I * TILE * DDIM);
        const char* gB = (const char*)(xb + (size_t)J * TILE * DDIM);
        #pragma unroll
        for (int p = 0; p < 8; ++p) {
            int row = p * 16 + r0;
            int gofs = row * 256 + chunk * 16;
            int lofs = gofs ^ ((row & 7) << 4);  // break 16-way bank conflict
            uint4 va = *(const uint4*)(gA + gofs);
            uint4 vb = *(const uint4*)(gB + gofs);
            *(uint4*)(ldsA + lofs) = va;
            *(uint4*)(ldsB + lofs) = vb;
        }
    }
    __syncthreads();

    int wave = tid >> 6, lane = tid & 63;
    int wR = (wave >> 1) * 64;   // 2x2 wave grid, 64x64 per wave
    int wC = (wave & 1) * 64;
    int lcol = lane & 15;        // fragment row/col index
    int lrow = lane >> 4;        // k-group

    f32x4 zero = {0.f, 0.f, 0.f, 0.f};
    f32x4 acc[4][4];
    #pragma unroll
    for (int r = 0; r < 4; ++r)
        #pragma unroll
        for (int c = 0; c < 4; ++c) acc[r][c] = zero;

    #pragma unroll
    for (int ks = 0; ks < 4; ++ks) {           // K = 128 = 4 x 32
        int kb = ks * 64 + lrow * 16;          // byte offset within row
        s16x8 a[4], b[4];
        #pragma unroll
        for (int r = 0; r < 4; ++r) {
            int rowA = wR + r * 16 + lcol;
            a[r] = *(const s16x8*)(ldsA + ((rowA * 256 + kb) ^ ((rowA & 7) << 4)));
            int rowB = wC + r * 16 + lcol;
            b[r] = *(const s16x8*)(ldsB + ((rowB * 256 + kb) ^ ((rowB & 7) << 4)));
        }
        #pragma unroll
        for (int r = 0; r < 4; ++r)
            #pragma unroll
            for (int c = 0; c < 4; ++c)
                acc[r][c] = __builtin_amdgcn_mfma_f32_16x16x32_bf16(a[r], b[c], acc[r][c], 0, 0, 0);
    }

    // ---- epilogue: d2 = sq_i + sq_j - 2*dot ; pe ; clip ; mask j>i ----
    float lsum = 0.0f;
    int ibase = I * TILE + wR + lrow * 4;
    int jbase = J * TILE + wC + lcol;
    float sqj[4];
    #pragma unroll
    for (int c = 0; c < 4; ++c) sqj[c] = sq[jbase + c * 16];

    #pragma unroll
    for (int r = 0; r < 4; ++r) {
        #pragma unroll
        for (int t = 0; t < 4; ++t) {
            int i = ibase + r * 16 + t;
            float si = sq[i];
            #pragma unroll
            for (int c = 0; c < 4; ++c) {
                int j = jbase + c * 16;
                if (j > i) {
                    float d2 = si + sqj[c] - 2.0f * acc[r][c][t];
                    d2 = fmaxf(d2, 1e-30f);   // masked-limit: pe->+inf->clip 1000
                    lsum += pe_clip_from_rinv(rsqrtf(d2));
                }
            }
        }
    }

    #pragma unroll
    for (int off = 32; off; off >>= 1) lsum += __shfl_down(lsum, off);

    __syncthreads();                 // all LDS fragment reads done; reuse LDS
    float* red = (float*)smem;
    if (lane == 0) red[wave] = lsum;
    __syncthreads();
    if (tid == 0) pp[bid] = red[0] + red[1] + red[2] + red[3];
}

__global__ __launch_bounds__(256) void reduce_kernel(
        const float* __restrict__ p0, int n0,
        const float* __restrict__ pp, int np, float* __restrict__ out) {
    int tid = threadIdx.x;
    double s0 = 0.0, sp = 0.0;
    for (int i = tid; i < n0; i += 256) s0 += (double)p0[i];
    for (int i = tid; i < np; i += 256) sp += (double)pp[i];
    __shared__ double sh0[256], shp[256];
    sh0[tid] = s0; shp[tid] = sp;
    __syncthreads();
    for (int s = 128; s; s >>= 1) {
        if (tid < s) { sh0[tid] += sh0[tid + s]; shp[tid] += shp[tid + s]; }
        __syncthreads();
    }
    if (tid == 0) {
        double cnt = (double)NROWS * (double)(NROWS - 1) * 0.5;
        out[0] = (float)(sh0[0] / (double)NROWS + shp[0] / cnt);
    }
}

extern "C" void kernel_launch(void* const* d_in, const int* in_sizes, int n_in,
                              void* d_out, int out_size, void* d_ws, size_t ws_size,
                              hipStream_t stream) {
    const float* x = (const float*)d_in[0];
    char* ws = (char*)d_ws;
    // ws layout: bf16 X copy (2 MB) | sq (32 KB) | loss0 partials (8 KB) | pair partials (16 KB)
    const size_t OFF_SQ = 2097152;
    const size_t OFF_P0 = OFF_SQ + 32768;
    const size_t OFF_PP = OFF_P0 + 8192;
    if (ws_size < OFF_PP + 16384) return;  // insufficient scratch -> fail validation cleanly

    unsigned int* xb_u32 = (unsigned int*)ws;
    __hip_bfloat16* xb = (__hip_bfloat16*)ws;
    float* sq = (float*)(ws + OFF_SQ);
    float* p0 = (float*)(ws + OFF_P0);
    float* pp = (float*)(ws + OFF_PP);

    convert_kernel<<<NROWS / 4, 256, 0, stream>>>(x, xb_u32, sq, p0);
    dim3 grid(TTILES, TTILES);
    pair_kernel<<<grid, 256, 0, stream>>>(xb, sq, pp);
    reduce_kernel<<<1, 256, 0, stream>>>(p0, NROWS / 4, pp, TTILES * TTILES, (float*)d_out);
}

// Round 2
// 55.960 us; speedup vs baseline: 1.0310x; 1.0310x over previous
//
#include <hip/hip_runtime.h>
#include <hip/hip_bf16.h>

// PTMLoss: loss0 (per-row distance-to-origin term) + mean over upper-tri
// pairwise-distance terms. bf16 MFMA Gram matrix, fragments loaded DIRECTLY
// from global (X_bf16 = 2 MB, L2-resident; per-tile A slice = 32 KB, L1-
// resident) — no LDS, no barriers, compact triangular grid for occupancy.

#define NROWS 8192
#define DDIM  128
#define TILE  128
#define TTILES (NROWS / TILE)   // 64
#define NTRI  (TTILES * (TTILES + 1) / 2)  // 2080
#define FEPS  1e-6f

typedef float f32x4 __attribute__((ext_vector_type(4)));
typedef short s16x8 __attribute__((ext_vector_type(8)));

__device__ __forceinline__ float pe_clip_from_rinv(float r) {
    // r = 1/d ; pe = 1/d^3 - 1/d^2 = r^3 - r^2 ; clip to [-1.5, 1000]
    float r2 = r * r;
    float v = r2 * r - r2;
    return fminf(fmaxf(v, -1.5f), 1000.0f);
}

// One wave per row: bf16 convert + fp32 row sum-of-squares + loss0 partial.
__global__ __launch_bounds__(256) void convert_kernel(
        const float* __restrict__ x, unsigned int* __restrict__ xb_u32,
        float* __restrict__ sq, float* __restrict__ p0) {
    int tid = threadIdx.x;
    int wave = tid >> 6, lane = tid & 63;
    int row = blockIdx.x * 4 + wave;

    float2 v = *(const float2*)(x + (size_t)row * DDIM + lane * 2);
    float s = v.x * v.x + v.y * v.y;
    float ex = v.x + FEPS, ey = v.y + FEPS;
    float e = ex * ex + ey * ey;

    __hip_bfloat16 b0 = __float2bfloat16(v.x);
    __hip_bfloat16 b1 = __float2bfloat16(v.y);
    unsigned short u0 = *reinterpret_cast<unsigned short*>(&b0);
    unsigned short u1 = *reinterpret_cast<unsigned short*>(&b1);
    xb_u32[(size_t)row * (DDIM / 2) + lane] = (unsigned)u0 | ((unsigned)u1 << 16);

    #pragma unroll
    for (int off = 32; off; off >>= 1) {
        s += __shfl_down(s, off);
        e += __shfl_down(e, off);
    }

    __shared__ float red[4];
    if (lane == 0) {
        sq[row] = s;
        red[wave] = pe_clip_from_rinv(rsqrtf(e));
    }
    __syncthreads();
    if (tid == 0) p0[blockIdx.x] = red[0] + red[1] + red[2] + red[3];
}

__device__ __forceinline__ int tri_off(int i) {
    // offset of row-tile i in condensed J>=I ordering, T = 64
    return i * TTILES - ((i * (i - 1)) >> 1);
}

// One 128x128 tile of S = X X^T per block; compact triangular grid.
__global__ __launch_bounds__(256, 4) void pair_kernel(
        const __hip_bfloat16* __restrict__ xb,
        const float* __restrict__ sq, float* __restrict__ pp) {
    int t = blockIdx.x;
    // decode t -> (I, J) with J >= I
    int I = (int)((2.0f * TTILES + 1.0f
                   - sqrtf((2.0f * TTILES + 1.0f) * (2.0f * TTILES + 1.0f)
                           - 8.0f * (float)t)) * 0.5f);
    while (tri_off(I + 1) <= t) ++I;
    while (tri_off(I) > t) --I;
    int J = I + (t - tri_off(I));

    int tid = threadIdx.x;
    int wave = tid >> 6, lane = tid & 63;
    int wR = (wave >> 1) * 64;   // 2x2 wave grid, 64x64 per wave
    int wC = (wave & 1) * 64;
    int lcol = lane & 15;        // fragment row index
    int lrow = lane >> 4;        // k-group

    // per-thread fragment base addresses (bf16 rows are 256 B)
    const char* A = (const char*)xb + ((size_t)(I * TILE + wR + lcol)) * 256 + lrow * 16;
    const char* B = (const char*)xb + ((size_t)(J * TILE + wC + lcol)) * 256 + lrow * 16;

    f32x4 zero = {0.f, 0.f, 0.f, 0.f};
    f32x4 acc[4][4];
    #pragma unroll
    for (int r = 0; r < 4; ++r)
        #pragma unroll
        for (int c = 0; c < 4; ++c) acc[r][c] = zero;

    #pragma unroll
    for (int ks = 0; ks < 4; ++ks) {           // K = 128 = 4 x 32
        s16x8 a[4], b[4];
        #pragma unroll
        for (int r = 0; r < 4; ++r) {
            a[r] = *(const s16x8*)(A + r * 16 * 256 + ks * 64);
            b[r] = *(const s16x8*)(B + r * 16 * 256 + ks * 64);
        }
        #pragma unroll
        for (int r = 0; r < 4; ++r)
            #pragma unroll
            for (int c = 0; c < 4; ++c)
                acc[r][c] = __builtin_amdgcn_mfma_f32_16x16x32_bf16(a[r], b[c], acc[r][c], 0, 0, 0);
    }

    // ---- epilogue: d2 = sq_i + sq_j - 2*dot ; pe ; clip ; mask j>i ----
    float lsum = 0.0f;
    int ibase = I * TILE + wR + lrow * 4;
    int jbase = J * TILE + wC + lcol;
    float sqj[4];
    #pragma unroll
    for (int c = 0; c < 4; ++c) sqj[c] = sq[jbase + c * 16];

    #pragma unroll
    for (int r = 0; r < 4; ++r) {
        #pragma unroll
        for (int u = 0; u < 4; ++u) {
            int i = ibase + r * 16 + u;
            float si = sq[i];
            #pragma unroll
            for (int c = 0; c < 4; ++c) {
                int j = jbase + c * 16;
                if (j > i) {
                    float d2 = si + sqj[c] - 2.0f * acc[r][c][u];
                    d2 = fmaxf(d2, 1e-30f);
                    lsum += pe_clip_from_rinv(rsqrtf(d2));
                }
            }
        }
    }

    #pragma unroll
    for (int off = 32; off; off >>= 1) lsum += __shfl_down(lsum, off);

    __shared__ float red[4];
    if (lane == 0) red[wave] = lsum;
    __syncthreads();
    if (tid == 0) pp[t] = red[0] + red[1] + red[2] + red[3];
}

__global__ __launch_bounds__(1024) void reduce_kernel(
        const float* __restrict__ p0, int n0,
        const float* __restrict__ pp, int np, float* __restrict__ out) {
    int tid = threadIdx.x;
    double s0 = 0.0, sp = 0.0;
    for (int i = tid; i < n0; i += 1024) s0 += (double)p0[i];
    for (int i = tid; i < np; i += 1024) sp += (double)pp[i];
    __shared__ double sh0[1024], shp[1024];
    sh0[tid] = s0; shp[tid] = sp;
    __syncthreads();
    for (int s = 512; s; s >>= 1) {
        if (tid < s) { sh0[tid] += sh0[tid + s]; shp[tid] += shp[tid + s]; }
        __syncthreads();
    }
    if (tid == 0) {
        double cnt = (double)NROWS * (double)(NROWS - 1) * 0.5;
        out[0] = (float)(sh0[0] / (double)NROWS + shp[0] / cnt);
    }
}

extern "C" void kernel_launch(void* const* d_in, const int* in_sizes, int n_in,
                              void* d_out, int out_size, void* d_ws, size_t ws_size,
                              hipStream_t stream) {
    const float* x = (const float*)d_in[0];
    char* ws = (char*)d_ws;
    // ws layout: bf16 X copy (2 MB) | sq (32 KB) | loss0 partials (8 KB) | pair partials
    const size_t OFF_SQ = 2097152;
    const size_t OFF_P0 = OFF_SQ + 32768;
    const size_t OFF_PP = OFF_P0 + 8192;
    if (ws_size < OFF_PP + NTRI * sizeof(float)) return;

    unsigned int* xb_u32 = (unsigned int*)ws;
    __hip_bfloat16* xb = (__hip_bfloat16*)ws;
    float* sq = (float*)(ws + OFF_SQ);
    float* p0 = (float*)(ws + OFF_P0);
    float* pp = (float*)(ws + OFF_PP);

    convert_kernel<<<NROWS / 4, 256, 0, stream>>>(x, xb_u32, sq, p0);
    pair_kernel<<<NTRI, 256, 0, stream>>>(xb, sq, pp);
    reduce_kernel<<<1, 1024, 0, stream>>>(p0, NROWS / 4, pp, NTRI, (float*)d_out);
}

// Round 3
// 53.743 us; speedup vs baseline: 1.0735x; 1.0412x over previous
//
#include <hip/hip_runtime.h>
#include <hip/hip_bf16.h>

// PTMLoss: loss0 + mean over upper-tri pairwise-distance terms.
// bf16 MFMA Gram tiles loaded directly from global (L2-resident), software-
// pipelined across tiles: while tile t's epilogue (~1000 cyc VALU) runs, the
// 32 fragment loads of tile t+1 are in flight. 512 persistent blocks.

#define NROWS 8192
#define DDIM  128
#define TILE  128
#define TTILES (NROWS / TILE)              // 64
#define NTRI  (TTILES * (TTILES + 1) / 2)  // 2080
#define NBLK  512
#define FEPS  1e-6f

typedef float f32x4 __attribute__((ext_vector_type(4)));
typedef short s16x8 __attribute__((ext_vector_type(8)));

__device__ __forceinline__ float pe_term(float d2) {
    // pe = r^3 - r^2, r = 1/sqrt(d2). Lower clip (-1.5) can never bind:
    // min over d of r^2(r-1) is -4/27. Upper clip 1000 kept (also NaN guard
    // via d2 floor: d2->1e-30 => v huge => clipped to 1000).
    float r = rsqrtf(fmaxf(d2, 1e-30f));
    float r2 = r * r;
    return fminf(r2 * r - r2, 1000.0f);
}

// One wave per row: bf16 convert + fp32 row sum-of-squares + loss0 partial.
__global__ __launch_bounds__(256) void convert_kernel(
        const float* __restrict__ x, unsigned int* __restrict__ xb_u32,
        float* __restrict__ sq, float* __restrict__ p0) {
    int tid = threadIdx.x;
    int wave = tid >> 6, lane = tid & 63;
    int row = blockIdx.x * 4 + wave;

    float2 v = *(const float2*)(x + (size_t)row * DDIM + lane * 2);
    float s = v.x * v.x + v.y * v.y;
    float ex = v.x + FEPS, ey = v.y + FEPS;
    float e = ex * ex + ey * ey;

    __hip_bfloat16 b0 = __float2bfloat16(v.x);
    __hip_bfloat16 b1 = __float2bfloat16(v.y);
    unsigned short u0 = *reinterpret_cast<unsigned short*>(&b0);
    unsigned short u1 = *reinterpret_cast<unsigned short*>(&b1);
    xb_u32[(size_t)row * (DDIM / 2) + lane] = (unsigned)u0 | ((unsigned)u1 << 16);

    #pragma unroll
    for (int off = 32; off; off >>= 1) {
        s += __shfl_down(s, off);
        e += __shfl_down(e, off);
    }

    __shared__ float red[4];
    if (lane == 0) {
        sq[row] = s;
        float r = rsqrtf(e);
        float r2 = r * r;
        red[wave] = fminf(fmaxf(r2 * r - r2, -1.5f), 1000.0f);
    }
    __syncthreads();
    if (tid == 0) p0[blockIdx.x] = red[0] + red[1] + red[2] + red[3];
}

__device__ __forceinline__ int tri_off(int i) {
    return i * TTILES - ((i * (i - 1)) >> 1);
}

__device__ __forceinline__ void decode_tile(int t, int& I, int& J) {
    float T2 = 2.0f * TTILES + 1.0f;
    int i = (int)((T2 - sqrtf(T2 * T2 - 8.0f * (float)t)) * 0.5f);
    while (tri_off(i + 1) <= t) ++i;
    while (tri_off(i) > t) --i;
    I = i;
    J = i + (t - tri_off(i));
}

__device__ __forceinline__ void load_frags(
        const char* __restrict__ xb, int I, int J, int rofsA, int rofsB, int kb,
        s16x8 fa[4][4], s16x8 fb[4][4]) {
    const char* A = xb + ((size_t)I * TILE + rofsA) * 256 + kb;
    const char* B = xb + ((size_t)J * TILE + rofsB) * 256 + kb;
    #pragma unroll
    for (int ks = 0; ks < 4; ++ks) {
        #pragma unroll
        for (int r = 0; r < 4; ++r) {
            fa[ks][r] = *(const s16x8*)(A + r * 16 * 256 + ks * 64);
            fb[ks][r] = *(const s16x8*)(B + r * 16 * 256 + ks * 64);
        }
    }
}

// Persistent-style: each block strides over tiles t = bid, bid+NBLK, ...
__global__ __launch_bounds__(256, 2) void pair_kernel(
        const __hip_bfloat16* __restrict__ xb_h,
        const float* __restrict__ sq, float* __restrict__ pp) {
    const char* xb = (const char*)xb_h;
    int tid = threadIdx.x;
    int wave = tid >> 6, lane = tid & 63;
    int wR = (wave >> 1) * 64;   // 2x2 wave grid, 64x64 per wave
    int wC = (wave & 1) * 64;
    int lcol = lane & 15;
    int lrow = lane >> 4;
    int rofsA = wR + lcol;       // fragment row offsets within tile
    int rofsB = wC + lcol;
    int kb = lrow * 16;          // byte offset of k-group within row

    float lsum = 0.0f;

    int t = blockIdx.x;
    if (t < NTRI) {
        int I, J;
        decode_tile(t, I, J);
        s16x8 fa[4][4], fb[4][4];
        load_frags(xb, I, J, rofsA, rofsB, kb, fa, fb);

        while (true) {
            // ---- MFMA for current tile ----
            f32x4 acc[4][4];
            #pragma unroll
            for (int r = 0; r < 4; ++r)
                #pragma unroll
                for (int c = 0; c < 4; ++c) acc[r][c] = (f32x4){0.f, 0.f, 0.f, 0.f};
            #pragma unroll
            for (int ks = 0; ks < 4; ++ks)
                #pragma unroll
                for (int r = 0; r < 4; ++r)
                    #pragma unroll
                    for (int c = 0; c < 4; ++c)
                        acc[r][c] = __builtin_amdgcn_mfma_f32_16x16x32_bf16(
                            fa[ks][r], fb[ks][c], acc[r][c], 0, 0, 0);

            int curI = I, curJ = J;

            // ---- prefetch next tile's fragments (hidden under epilogue) ----
            int tn = t + NBLK;
            if (tn < NTRI) {
                decode_tile(tn, I, J);
                load_frags(xb, I, J, rofsA, rofsB, kb, fa, fb);
            }

            // ---- epilogue: d2 = sq_i + sq_j - 2*dot ; pe ; clip ----
            int ibase = curI * TILE + wR + lrow * 4;
            int jbase = curJ * TILE + wC + lcol;
            float sqj[4], sqi[4][4];
            #pragma unroll
            for (int c = 0; c < 4; ++c) sqj[c] = sq[jbase + c * 16];
            #pragma unroll
            for (int r = 0; r < 4; ++r)
                #pragma unroll
                for (int u = 0; u < 4; ++u) sqi[r][u] = sq[ibase + r * 16 + u];

            if (curI != curJ) {
                // off-diagonal: every element counts, branchless
                #pragma unroll
                for (int r = 0; r < 4; ++r)
                    #pragma unroll
                    for (int u = 0; u < 4; ++u) {
                        float si = sqi[r][u];
                        #pragma unroll
                        for (int c = 0; c < 4; ++c)
                            lsum += pe_term(si + sqj[c] - 2.0f * acc[r][c][u]);
                    }
            } else {
                // diagonal tile: local mask j > i
                int il0 = wR + lrow * 4;
                int jl0 = wC + lcol;
                #pragma unroll
                for (int r = 0; r < 4; ++r)
                    #pragma unroll
                    for (int u = 0; u < 4; ++u) {
                        int il = il0 + r * 16 + u;
                        float si = sqi[r][u];
                        #pragma unroll
                        for (int c = 0; c < 4; ++c) {
                            if (jl0 + c * 16 > il)
                                lsum += pe_term(si + sqj[c] - 2.0f * acc[r][c][u]);
                        }
                    }
            }

            t = tn;
            if (t >= NTRI) break;
        }
    }

    // ---- one reduce per block ----
    #pragma unroll
    for (int off = 32; off; off >>= 1) lsum += __shfl_down(lsum, off);
    __shared__ float red[4];
    if (lane == 0) red[wave] = lsum;
    __syncthreads();
    if (tid == 0) pp[blockIdx.x] = red[0] + red[1] + red[2] + red[3];
}

__global__ __launch_bounds__(1024) void reduce_kernel(
        const float* __restrict__ p0, int n0,
        const float* __restrict__ pp, int np, float* __restrict__ out) {
    int tid = threadIdx.x;
    double s0 = 0.0, sp = 0.0;
    for (int i = tid; i < n0; i += 1024) s0 += (double)p0[i];
    for (int i = tid; i < np; i += 1024) sp += (double)pp[i];
    __shared__ double sh0[1024], shp[1024];
    sh0[tid] = s0; shp[tid] = sp;
    __syncthreads();
    for (int s = 512; s; s >>= 1) {
        if (tid < s) { sh0[tid] += sh0[tid + s]; shp[tid] += shp[tid + s]; }
        __syncthreads();
    }
    if (tid == 0) {
        double cnt = (double)NROWS * (double)(NROWS - 1) * 0.5;
        out[0] = (float)(sh0[0] / (double)NROWS + shp[0] / cnt);
    }
}

extern "C" void kernel_launch(void* const* d_in, const int* in_sizes, int n_in,
                              void* d_out, int out_size, void* d_ws, size_t ws_size,
                              hipStream_t stream) {
    const float* x = (const float*)d_in[0];
    char* ws = (char*)d_ws;
    const size_t OFF_SQ = 2097152;
    const size_t OFF_P0 = OFF_SQ + 32768;
    const size_t OFF_PP = OFF_P0 + 8192;
    if (ws_size < OFF_PP + NBLK * sizeof(float)) return;

    unsigned int* xb_u32 = (unsigned int*)ws;
    __hip_bfloat16* xb = (__hip_bfloat16*)ws;
    float* sq = (float*)(ws + OFF_SQ);
    float* p0 = (float*)(ws + OFF_P0);
    float* pp = (float*)(ws + OFF_PP);

    convert_kernel<<<NROWS / 4, 256, 0, stream>>>(x, xb_u32, sq, p0);
    pair_kernel<<<NBLK, 256, 0, stream>>>(xb, sq, pp);
    reduce_kernel<<<1, 1024, 0, stream>>>(p0, NROWS / 4, pp, NBLK, (float*)d_out);
}

// Round 4
// 36.065 us; speedup vs baseline: 1.5997x; 1.4902x over previous
//
#include <hip/hip_runtime.h>
#include <hip/hip_bf16.h>

// PTMLoss: loss0 + mean over upper-tri pairwise-distance terms.
// R4: LDS staging with J-strip panel reuse to cut vector-memory request
// count ~4x (flat-time evidence across R1-R3 points at TA/L1 request
// throughput, not occupancy/latency). Block = (I-panel, 4 J-tiles):
// stage A once, stage B per tile, fragments from swizzled LDS.

#define NROWS 8192
#define DDIM  128
#define TILE  128
#define TTILES (NROWS / TILE)              // 64
#define LSTRIP 4
#define NBLKP  544                         // sum_I ceil((64-I)/4)
#define FEPS  1e-6f

typedef float f32x4 __attribute__((ext_vector_type(4)));
typedef short s16x8 __attribute__((ext_vector_type(8)));

__device__ __forceinline__ float pe_term(float d2) {
    // pe = r^3 - r^2, r = 1/sqrt(d2); lower clip -1.5 never binds (min -4/27)
    float r = rsqrtf(fmaxf(d2, 1e-30f));
    float r2 = r * r;
    return fminf(r2 * r - r2, 1000.0f);
}

// One wave per row: bf16 convert + fp32 row sum-of-squares + loss0 partial.
__global__ __launch_bounds__(256) void convert_kernel(
        const float* __restrict__ x, unsigned int* __restrict__ xb_u32,
        float* __restrict__ sq, float* __restrict__ p0) {
    int tid = threadIdx.x;
    int wave = tid >> 6, lane = tid & 63;
    int row = blockIdx.x * 4 + wave;

    float2 v = *(const float2*)(x + (size_t)row * DDIM + lane * 2);
    float s = v.x * v.x + v.y * v.y;
    float ex = v.x + FEPS, ey = v.y + FEPS;
    float e = ex * ex + ey * ey;

    __hip_bfloat16 b0 = __float2bfloat16(v.x);
    __hip_bfloat16 b1 = __float2bfloat16(v.y);
    unsigned short u0 = *reinterpret_cast<unsigned short*>(&b0);
    unsigned short u1 = *reinterpret_cast<unsigned short*>(&b1);
    xb_u32[(size_t)row * (DDIM / 2) + lane] = (unsigned)u0 | ((unsigned)u1 << 16);

    #pragma unroll
    for (int off = 32; off; off >>= 1) {
        s += __shfl_down(s, off);
        e += __shfl_down(e, off);
    }

    __shared__ float red[4];
    if (lane == 0) {
        sq[row] = s;
        float r = rsqrtf(e);
        float r2 = r * r;
        red[wave] = fminf(fmaxf(r2 * r - r2, -1.5f), 1000.0f);
    }
    __syncthreads();
    if (tid == 0) p0[blockIdx.x] = red[0] + red[1] + red[2] + red[3];
}

// Stage one 128x128 bf16 tile (32 KB) into LDS with per-row XOR swizzle.
// 512 threads, 4 x 16B chunks each; global reads contiguous 1KB per wave-load.
__device__ __forceinline__ void stage_tile(const char* __restrict__ g,
                                           char* lds, int tid) {
    int l = tid & 63, w = tid >> 6;
    uint4 v[4];
    #pragma unroll
    for (int p = 0; p < 4; ++p)
        v[p] = *(const uint4*)(g + ((w * 4 + p) * 64 + l) * 16);
    #pragma unroll
    for (int p = 0; p < 4; ++p) {
        int chunk = (w * 4 + p) * 64 + l;     // 0..2047
        int row = chunk >> 4, c = chunk & 15;
        *(uint4*)(lds + row * 256 + ((c * 16) ^ ((row & 7) << 4))) = v[p];
    }
}

__global__ __launch_bounds__(512, 4) void pair_kernel(
        const __hip_bfloat16* __restrict__ xb_h,
        const float* __restrict__ sq, float* __restrict__ pp) {
    const char* xb = (const char*)xb_h;
    __shared__ char smem[65536];
    char* ldsA = smem;
    char* ldsB = smem + 32768;

    // decode blockIdx.x -> (I, j0..jend) strip
    int s = blockIdx.x, I = 0;
    int ns = (TTILES + LSTRIP - 1) / LSTRIP;
    while (s >= ns) { s -= ns; ++I; ns = (TTILES - I + LSTRIP - 1) / LSTRIP; }
    int j0 = I + s * LSTRIP;
    int jend = j0 + LSTRIP; if (jend > TTILES) jend = TTILES;

    int tid = threadIdx.x;
    int wave = tid >> 6, lane = tid & 63;
    int wR = (wave >> 2) * 64;    // 2x4 wave grid: 64x32 per wave
    int wC = (wave & 3) * 32;
    int lcol = lane & 15;
    int lrow = lane >> 4;

    // A-panel fixed per block: stage once, hoist sq_i loads
    stage_tile(xb + (size_t)I * TILE * 256, ldsA, tid);
    float sqi[4][4];
    {
        int ib = I * TILE + wR + lrow * 4;
        #pragma unroll
        for (int r = 0; r < 4; ++r)
            #pragma unroll
            for (int u = 0; u < 4; ++u) sqi[r][u] = sq[ib + r * 16 + u];
    }

    float lsum = 0.0f;

    for (int J = j0; J < jend; ++J) {
        stage_tile(xb + (size_t)J * TILE * 256, ldsB, tid);
        __syncthreads();   // staged data visible (A on first iter, B each iter)

        f32x4 acc[4][2];
        #pragma unroll
        for (int r = 0; r < 4; ++r)
            #pragma unroll
            for (int c = 0; c < 2; ++c) acc[r][c] = (f32x4){0.f, 0.f, 0.f, 0.f};

        #pragma unroll
        for (int ks = 0; ks < 4; ++ks) {
            int kb = ks * 64 + lrow * 16;
            s16x8 a[4], b[2];
            #pragma unroll
            for (int r = 0; r < 4; ++r) {
                int row = wR + r * 16 + lcol;
                a[r] = *(const s16x8*)(ldsA + row * 256 + (kb ^ ((row & 7) << 4)));
            }
            #pragma unroll
            for (int c = 0; c < 2; ++c) {
                int row = wC + c * 16 + lcol;
                b[c] = *(const s16x8*)(ldsB + row * 256 + (kb ^ ((row & 7) << 4)));
            }
            #pragma unroll
            for (int r = 0; r < 4; ++r)
                #pragma unroll
                for (int c = 0; c < 2; ++c)
                    acc[r][c] = __builtin_amdgcn_mfma_f32_16x16x32_bf16(
                        a[r], b[c], acc[r][c], 0, 0, 0);
        }

        // epilogue
        int jbase = J * TILE + wC + lcol;
        float sqj[2];
        #pragma unroll
        for (int c = 0; c < 2; ++c) sqj[c] = sq[jbase + c * 16];

        if (I != J) {
            #pragma unroll
            for (int r = 0; r < 4; ++r)
                #pragma unroll
                for (int u = 0; u < 4; ++u) {
                    float si = sqi[r][u];
                    #pragma unroll
                    for (int c = 0; c < 2; ++c)
                        lsum += pe_term(si + sqj[c] - 2.0f * acc[r][c][u]);
                }
        } else {
            int il0 = wR + lrow * 4;
            int jl0 = wC + lcol;
            #pragma unroll
            for (int r = 0; r < 4; ++r)
                #pragma unroll
                for (int u = 0; u < 4; ++u) {
                    int il = il0 + r * 16 + u;
                    float si = sqi[r][u];
                    #pragma unroll
                    for (int c = 0; c < 2; ++c) {
                        if (jl0 + c * 16 > il)
                            lsum += pe_term(si + sqj[c] - 2.0f * acc[r][c][u]);
                    }
                }
        }
        __syncthreads();   // all LDS reads done before next stage overwrites B
    }

    #pragma unroll
    for (int off = 32; off; off >>= 1) lsum += __shfl_down(lsum, off);
    __shared__ float red[8];
    if (lane == 0) red[wave] = lsum;
    __syncthreads();
    if (tid == 0) {
        float t = 0.f;
        #pragma unroll
        for (int w = 0; w < 8; ++w) t += red[w];
        pp[blockIdx.x] = t;
    }
}

__global__ __launch_bounds__(1024) void reduce_kernel(
        const float* __restrict__ p0, int n0,
        const float* __restrict__ pp, int np, float* __restrict__ out) {
    int tid = threadIdx.x;
    double s0 = 0.0, sp = 0.0;
    for (int i = tid; i < n0; i += 1024) s0 += (double)p0[i];
    for (int i = tid; i < np; i += 1024) sp += (double)pp[i];
    __shared__ double sh0[1024], shp[1024];
    sh0[tid] = s0; shp[tid] = sp;
    __syncthreads();
    for (int s = 512; s; s >>= 1) {
        if (tid < s) { sh0[tid] += sh0[tid + s]; shp[tid] += shp[tid + s]; }
        __syncthreads();
    }
    if (tid == 0) {
        double cnt = (double)NROWS * (double)(NROWS - 1) * 0.5;
        out[0] = (float)(sh0[0] / (double)NROWS + shp[0] / cnt);
    }
}

extern "C" void kernel_launch(void* const* d_in, const int* in_sizes, int n_in,
                              void* d_out, int out_size, void* d_ws, size_t ws_size,
                              hipStream_t stream) {
    const float* x = (const float*)d_in[0];
    char* ws = (char*)d_ws;
    const size_t OFF_SQ = 2097152;
    const size_t OFF_P0 = OFF_SQ + 32768;
    const size_t OFF_PP = OFF_P0 + 8192;
    if (ws_size < OFF_PP + NBLKP * sizeof(float)) return;

    unsigned int* xb_u32 = (unsigned int*)ws;
    __hip_bfloat16* xb = (__hip_bfloat16*)ws;
    float* sq = (float*)(ws + OFF_SQ);
    float* p0 = (float*)(ws + OFF_P0);
    float* pp = (float*)(ws + OFF_PP);

    convert_kernel<<<NROWS / 4, 256, 0, stream>>>(x, xb_u32, sq, p0);
    pair_kernel<<<NBLKP, 512, 0, stream>>>(xb, sq, pp);
    reduce_kernel<<<1, 1024, 0, stream>>>(p0, NROWS / 4, pp, NBLKP, (float*)d_out);
}